// Round 1
// baseline (515.126 us; speedup 1.0000x reference)
//
#include <hip/hip_runtime.h>
#include <math.h>

#define NN 16384
#define DEG 20
#define EE (NN*DEG)
#define RMAXF 3.5f

// soft_unit_step: exp(-1/x) for x>0 else 0
__device__ __forceinline__ float su_f(float x) {
    return x > 0.0f ? __expf(-1.0f / x) : 0.0f;
}

// ---------------------------------------------------------------------------
// q_kernel: per-node equivariant linear. q layout matches f: [N, 32]
// (8 scalars, then 8 vectors * 3 comps, o-major, c fastest)
// ---------------------------------------------------------------------------
__global__ __launch_bounds__(256) void q_kernel(
    const float* __restrict__ f, const float* __restrict__ Wqs,
    const float* __restrict__ Wqv, float* __restrict__ q)
{
    int gid = blockIdx.x * 256 + threadIdx.x;
    int n = gid >> 5, k = gid & 31;
    const float* fr = f + (size_t)n * 32;
    float acc = 0.0f;
    if (k < 8) {
        #pragma unroll
        for (int i = 0; i < 8; i++) acc += fr[i] * Wqs[i * 8 + k];
    } else {
        int kk = k - 8;
        int o = kk / 3, c = kk - 3 * (kk / 3);
        #pragma unroll
        for (int i = 0; i < 8; i++) acc += fr[8 + i * 3 + c] * Wqv[i * 8 + o];
    }
    q[(size_t)n * 32 + k] = acc * 0.35355339059327373f; // 1/sqrt(8)
}

// ---------------------------------------------------------------------------
// edge_kernel: block = 256 threads = 4 waves, 16 edges per block (4/wave).
// Computes emb -> h (silu) -> w (k & v nets) -> tensor products -> logits.
// Writes logits[E], cutoff[E], v[E][32] to workspace.
// ---------------------------------------------------------------------------
__global__ __launch_bounds__(256) void edge_kernel(
    const float* __restrict__ f,   const float* __restrict__ pos,
    const float* __restrict__ Wk1, const float* __restrict__ Wk2,
    const float* __restrict__ Wv1, const float* __restrict__ Wv2,
    const float* __restrict__ Wds, const float* __restrict__ Wdv,
    const int* __restrict__ esrc,  const int* __restrict__ edst,
    const float* __restrict__ q,
    float* __restrict__ logits, float* __restrict__ cutoff,
    float* __restrict__ vout)
{
    __shared__ float s_s1[16][3];                 // sqrt(3)*unit vec per edge
    __shared__ float s_emb[16][10];               // radial basis
    __shared__ float s_g[16][32];                 // f[src] rows
    __shared__ float s_q[16][32];                 // q[dst] rows
    __shared__ __align__(16) float s_h[4][64][8]; // [wave][hidden][hk e0..3, hv e0..3]
    __shared__ __align__(16) float s_w[4][4][2][256]; // [wave][e][net k/v][256 tp weights]
    __shared__ float s_k[16][32];                 // ks[8], kv[8][3] per edge

    const int t = threadIdx.x;
    const int wave = t >> 6, lane = t & 63;
    const int e0 = blockIdx.x * 16;

    // ---- phase 1: per-edge geometry + radial basis (threads 0..15) ----
    if (t < 16) {
        int e = e0 + t;
        int s = esrc[e], d = edst[e];
        float vx = pos[s * 3 + 0] - pos[d * 3 + 0];
        float vy = pos[s * 3 + 1] - pos[d * 3 + 1];
        float vz = pos[s * 3 + 2] - pos[d * 3 + 2];
        float r = sqrtf(vx * vx + vy * vy + vz * vz);
        float invr = 1.0f / r;
        const float sqrt3 = 1.7320508075688772f;
        s_s1[t][0] = sqrt3 * vx * invr;
        s_s1[t][1] = sqrt3 * vy * invr;
        s_s1[t][2] = sqrt3 * vz * invr;
        cutoff[e] = su_f(10.0f * (1.0f - r / RMAXF));
        const float step = RMAXF / 11.0f;
        const float invstep = 11.0f / RMAXF;
        const float K = 26.66929988626f; // 1.14136*e^2*sqrt(10)
        #pragma unroll
        for (int j = 0; j < 10; j++) {
            float dd = (r - step * (float)(j + 1)) * invstep;
            s_emb[t][j] = K * su_f(dd + 1.0f) * su_f(1.0f - dd);
        }
    }
    // ---- phase 1b: stage gathered f[src] and q[dst] rows ----
    {
        int el = t >> 4, j = t & 15;
        int e = e0 + el;
        int s = esrc[e], d = edst[e];
        s_g[el][j]      = f[(size_t)s * 32 + j];
        s_g[el][16 + j] = f[(size_t)s * 32 + 16 + j];
        s_q[el][j]      = q[(size_t)d * 32 + j];
        s_q[el][16 + j] = q[(size_t)d * 32 + 16 + j];
    }
    __syncthreads();

    // ---- phase 2: GEMM1 + silu (h for both nets), wave handles its 4 edges ----
    {
        const float invsq10 = 0.31622776601683794f; // 1/sqrt(10)
        #pragma unroll
        for (int e = 0; e < 4; e++) {
            int el = wave * 4 + e;
            float ak = 0.0f, av = 0.0f;
            #pragma unroll
            for (int j = 0; j < 10; j++) {
                float ej = s_emb[el][j];
                ak = fmaf(ej, Wk1[j * 64 + lane], ak);
                av = fmaf(ej, Wv1[j * 64 + lane], av);
            }
            ak *= invsq10; av *= invsq10;
            s_h[wave][lane][e]     = ak / (1.0f + __expf(-ak)); // silu
            s_h[wave][lane][4 + e] = av / (1.0f + __expf(-av));
        }
    }
    __syncthreads();

    // ---- phase 3: GEMM2 (h[64] @ W2[64,256]) for both nets, 4 edges blocked ----
    {
        const float4* W2k = reinterpret_cast<const float4*>(Wk2);
        const float4* W2v = reinterpret_cast<const float4*>(Wv2);
        float awk[4][4] = {};
        float awv[4][4] = {};
        #pragma unroll 4
        for (int hh = 0; hh < 64; hh++) {
            float4 wkr = W2k[hh * 64 + lane];
            float4 wvr = W2v[hh * 64 + lane];
            float4 hk4 = *reinterpret_cast<const float4*>(&s_h[wave][hh][0]);
            float4 hv4 = *reinterpret_cast<const float4*>(&s_h[wave][hh][4]);
            float hks[4] = {hk4.x, hk4.y, hk4.z, hk4.w};
            float hvs[4] = {hv4.x, hv4.y, hv4.z, hv4.w};
            #pragma unroll
            for (int e = 0; e < 4; e++) {
                awk[e][0] = fmaf(hks[e], wkr.x, awk[e][0]);
                awk[e][1] = fmaf(hks[e], wkr.y, awk[e][1]);
                awk[e][2] = fmaf(hks[e], wkr.z, awk[e][2]);
                awk[e][3] = fmaf(hks[e], wkr.w, awk[e][3]);
                awv[e][0] = fmaf(hvs[e], wvr.x, awv[e][0]);
                awv[e][1] = fmaf(hvs[e], wvr.y, awv[e][1]);
                awv[e][2] = fmaf(hvs[e], wvr.z, awv[e][2]);
                awv[e][3] = fmaf(hvs[e], wvr.w, awv[e][3]);
            }
        }
        const float inv8 = 0.125f; // 1/sqrt(64)
        #pragma unroll
        for (int e = 0; e < 4; e++) {
            float4 tk = {awk[e][0] * inv8, awk[e][1] * inv8, awk[e][2] * inv8, awk[e][3] * inv8};
            float4 tv = {awv[e][0] * inv8, awv[e][1] * inv8, awv[e][2] * inv8, awv[e][3] * inv8};
            *reinterpret_cast<float4*>(&s_w[wave][e][0][lane * 4]) = tk;
            *reinterpret_cast<float4*>(&s_w[wave][e][1][lane * 4]) = tv;
        }
    }
    __syncthreads();

    // ---- phase 4: tensor products (k and v), 16 threads per edge ----
    {
        int el = t >> 4, role = t & 15;
        int e = e0 + el;
        float s1x = s_s1[el][0], s1y = s_s1[el][1], s1z = s_s1[el][2];
        const float inv_sqrt3 = 0.5773502691896258f;
        float a[8], b[8];
        #pragma unroll
        for (int i = 0; i < 8; i++) {
            a[i] = s_g[el][i];
            b[i] = (s_g[el][8 + i * 3 + 0] * s1x +
                    s_g[el][8 + i * 3 + 1] * s1y +
                    s_g[el][8 + i * 3 + 2] * s1z) * inv_sqrt3;
        }
        const float* wk = s_w[el >> 2][el & 3][0];
        const float* wv = s_w[el >> 2][el & 3][1];
        const float nrm = 0.25f; // 1/(sqrt(8)*sqrt(2))
        if (role < 8) {
            int o = role;
            float ks = 0.0f, vs = 0.0f;
            #pragma unroll
            for (int i = 0; i < 8; i++) {
                ks += a[i] * wk[i * 8 + o] + b[i] * wk[64 + i * 8 + o];
                vs += a[i] * wv[i * 8 + o] + b[i] * wv[64 + i * 8 + o];
            }
            s_k[el][o] = ks * nrm;
            vout[(size_t)e * 32 + o] = vs * nrm;
        } else {
            int o = role - 8;
            #pragma unroll
            for (int c = 0; c < 3; c++) {
                float uk = 0.0f, tk = 0.0f, uv = 0.0f, tv = 0.0f;
                #pragma unroll
                for (int i = 0; i < 8; i++) {
                    float gvic = s_g[el][8 + i * 3 + c];
                    uk += a[i] * wk[128 + i * 8 + o];
                    tk = fmaf(gvic, wk[192 + i * 8 + o], tk);
                    uv += a[i] * wv[128 + i * 8 + o];
                    tv = fmaf(gvic, wv[192 + i * 8 + o], tv);
                }
                float s1c = s_s1[el][c];
                s_k[el][8 + o * 3 + c] = nrm * (s1c * uk + tk);
                vout[(size_t)e * 32 + 8 + o * 3 + c] = nrm * (s1c * uv + tv);
            }
        }
    }
    __syncthreads();

    // ---- phase 5: logits (dot tensor product q . k), 16 threads per edge ----
    {
        int el = t >> 4, role = t & 15;
        int e = e0 + el;
        const float inv_sqrt3 = 0.5773502691896258f;
        float part = 0.0f;
        #pragma unroll
        for (int kk = 0; kk < 4; kk++) {
            int p = role * 4 + kk;
            int i = p >> 3, j = p & 7;
            float qs_i = s_q[el][i];
            float ks_j = s_k[el][j];
            float dv = s_q[el][8 + i * 3 + 0] * s_k[el][8 + j * 3 + 0]
                     + s_q[el][8 + i * 3 + 1] * s_k[el][8 + j * 3 + 1]
                     + s_q[el][8 + i * 3 + 2] * s_k[el][8 + j * 3 + 2];
            part += qs_i * ks_j * Wds[i * 8 + j] + dv * Wdv[i * 8 + j] * inv_sqrt3;
        }
        part += __shfl_xor(part, 1);
        part += __shfl_xor(part, 2);
        part += __shfl_xor(part, 4);
        part += __shfl_xor(part, 8);
        if (role == 0) logits[e] = part * 0.08838834764831845f; // 1/(8*sqrt(2))
    }
}

// ---------------------------------------------------------------------------
// out_kernel: one half-wave (32 lanes) per node. Segment softmax over the
// node's 20 contiguous edges + coef-weighted accumulation of v rows.
// ---------------------------------------------------------------------------
__global__ __launch_bounds__(256) void out_kernel(
    const float* __restrict__ logits, const float* __restrict__ cutoff,
    const float* __restrict__ v, float* __restrict__ out)
{
    int t = threadIdx.x, wave = t >> 6, lane = t & 63;
    int half = lane >> 5, hl = lane & 31;
    int n = blockIdx.x * 8 + wave * 2 + half;

    float lg = -INFINITY, cw = 0.0f;
    if (hl < DEG) {
        lg = logits[(size_t)n * DEG + hl];
        cw = cutoff[(size_t)n * DEG + hl];
    }
    // max over the 32-lane half (xor masks 16..1 stay within the half)
    float mx = lg;
    mx = fmaxf(mx, __shfl_xor(mx, 16));
    mx = fmaxf(mx, __shfl_xor(mx, 8));
    mx = fmaxf(mx, __shfl_xor(mx, 4));
    mx = fmaxf(mx, __shfl_xor(mx, 2));
    mx = fmaxf(mx, __shfl_xor(mx, 1));

    float ew = cw * __expf(lg - mx); // lanes >= DEG: cw=0, exp(-inf)=0
    float z = ew;
    z += __shfl_xor(z, 16);
    z += __shfl_xor(z, 8);
    z += __shfl_xor(z, 4);
    z += __shfl_xor(z, 2);
    z += __shfl_xor(z, 1);
    z = (z == 0.0f) ? 1.0f : z;
    float coef = sqrtf(ew / z + 1e-12f);

    // lane hl (0..31) accumulates output element hl over the 20 edges
    float acc = 0.0f;
    int base = half * 32;
    #pragma unroll
    for (int ee = 0; ee < DEG; ee++) {
        float ce = __shfl(coef, base + ee);
        acc = fmaf(ce, v[((size_t)n * DEG + ee) * 32 + hl], acc);
    }
    out[(size_t)n * 32 + hl] = acc;
}

// ---------------------------------------------------------------------------
extern "C" void kernel_launch(void* const* d_in, const int* in_sizes, int n_in,
                              void* d_out, int out_size, void* d_ws, size_t ws_size,
                              hipStream_t stream) {
    const float* f    = (const float*)d_in[0];
    const float* pos  = (const float*)d_in[1];
    const float* Wqs  = (const float*)d_in[2];
    const float* Wqv  = (const float*)d_in[3];
    const float* Wk1  = (const float*)d_in[4];
    const float* Wk2  = (const float*)d_in[5];
    const float* Wv1  = (const float*)d_in[6];
    const float* Wv2  = (const float*)d_in[7];
    const float* Wds  = (const float*)d_in[8];
    const float* Wdv  = (const float*)d_in[9];
    const int* esrc   = (const int*)d_in[10];
    const int* edst   = (const int*)d_in[11];
    float* out        = (float*)d_out;

    float* ws   = (float*)d_ws;
    float* qbuf = ws;                       // N*32
    float* lbuf = qbuf + (size_t)NN * 32;   // E
    float* cbuf = lbuf + (size_t)EE;        // E
    float* vbuf = cbuf + (size_t)EE;        // E*32

    q_kernel<<<dim3((NN * 32) / 256), dim3(256), 0, stream>>>(f, Wqs, Wqv, qbuf);
    edge_kernel<<<dim3(EE / 16), dim3(256), 0, stream>>>(
        f, pos, Wk1, Wk2, Wv1, Wv2, Wds, Wdv, esrc, edst, qbuf, lbuf, cbuf, vbuf);
    out_kernel<<<dim3(NN / 8), dim3(256), 0, stream>>>(lbuf, cbuf, vbuf, out);
}

// Round 3
// 362.438 us; speedup vs baseline: 1.4213x; 1.4213x over previous
//
#include <hip/hip_runtime.h>
#include <hip/hip_bf16.h>
#include <math.h>

#define NN 16384
#define DEG 20
#define EE (NN*DEG)
#define RMAXF 3.5f

typedef __attribute__((ext_vector_type(8))) short short8;
typedef __attribute__((ext_vector_type(4))) float f32x4;

// soft_unit_step: exp(-1/x) for x>0 else 0
__device__ __forceinline__ float su_f(float x) {
    return x > 0.0f ? __expf(-1.0f / x) : 0.0f;
}
__device__ __forceinline__ ushort f2bf(float x) {
    __hip_bfloat16 h = __float2bfloat16(x);
    return *reinterpret_cast<ushort*>(&h);
}

// ---------------------------------------------------------------------------
// q_kernel: per-node equivariant linear (round-1 verbatim, proven).
// ---------------------------------------------------------------------------
__global__ __launch_bounds__(256) void q_kernel(
    const float* __restrict__ f, const float* __restrict__ Wqs,
    const float* __restrict__ Wqv, float* __restrict__ q)
{
    int gid = blockIdx.x * 256 + threadIdx.x;
    int n = gid >> 5, k = gid & 31;
    const float* fr = f + (size_t)n * 32;
    float acc = 0.0f;
    if (k < 8) {
        #pragma unroll
        for (int i = 0; i < 8; i++) acc += fr[i] * Wqs[i * 8 + k];
    } else {
        int kk = k - 8;
        int o = kk / 3, c = kk - 3 * (kk / 3);
        #pragma unroll
        for (int i = 0; i < 8; i++) acc += fr[8 + i * 3 + c] * Wqv[i * 8 + o];
    }
    q[(size_t)n * 32 + k] = acc * 0.35355339059327373f; // 1/sqrt(8)
}

// ---------------------------------------------------------------------------
// pack_kernel: prepack W2 (both nets, x0.125 = 1/sqrt(64)) into bf16 MFMA
// B-fragment layout. B-frag lane(q=lane>>4, n=lane&15): 8 bf16 =
// W2[k = s*32 + q*8 + j][col = tt*16 + n], j=0..7.
// wsB2 layout: [net][kstep s][tile tt (16)][lane (64)] as uint4.
// ---------------------------------------------------------------------------
__global__ __launch_bounds__(256) void pack_kernel(
    const float* __restrict__ Wk2, const float* __restrict__ Wv2,
    uint4* __restrict__ wsB2)
{
    int tid = blockIdx.x * 256 + threadIdx.x;
    if (tid >= 4096) return;
    int net = tid >> 11, s = (tid >> 10) & 1, tt = (tid >> 6) & 15, lane = tid & 63;
    int q = lane >> 4, n = lane & 15, col = tt * 16 + n;
    const float* W2 = net ? Wv2 : Wk2;
    unsigned int r[4];
    #pragma unroll
    for (int jj = 0; jj < 4; jj++) {
        int k0 = s * 32 + q * 8 + 2 * jj;
        unsigned int lo = f2bf(W2[k0 * 256 + col] * 0.125f);
        unsigned int hi = f2bf(W2[(k0 + 1) * 256 + col] * 0.125f);
        r[jj] = lo | (hi << 16);
    }
    wsB2[tid] = make_uint4(r[0], r[1], r[2], r[3]);
}

// ---------------------------------------------------------------------------
// edge_kernel: block = 256 threads = 4 waves, 16 edges per block.
// Round-1 structure; only GEMM2 replaced by MFMA (net-sequential, LDS
// restage of B fragments between k-net and v-net).
// ---------------------------------------------------------------------------
__global__ __launch_bounds__(256, 2) void edge_kernel(
    const float* __restrict__ f,   const float* __restrict__ pos,
    const float* __restrict__ Wk1, const float* __restrict__ Wv1,
    const float* __restrict__ Wds, const float* __restrict__ Wdv,
    const int* __restrict__ esrc,  const int* __restrict__ edst,
    const float* __restrict__ q,   const uint4* __restrict__ wsB2,
    float* __restrict__ logits, float* __restrict__ cutoff,
    float* __restrict__ vout)
{
    __shared__ __align__(16) uint4  s_B2[2][16][64];   // 32 KB, one net at a time
    __shared__ __align__(16) float  s_w[16][260];      // 16.25 KB (pad +4: 2-way only)
    __shared__ __align__(16) ushort s_hb[2][16][64];   // 4 KB, bf16 h, XOR-swizzled
    __shared__ float s_g[16][32];                      // f[src] rows
    __shared__ float s_q[16][32];                      // q[dst] rows
    __shared__ float s_k[16][32];                      // k tensor-product output
    __shared__ float s_emb[16][10];
    __shared__ float s_s1[16][4];

    const int t = threadIdx.x;
    const int wave = t >> 6, lane = t & 63;
    const int qd = lane >> 4, n = lane & 15;
    const int e0 = blockIdx.x * 16;
    uint4* s_B2f = &s_B2[0][0][0];

    // ---- phase 1: per-edge geometry + radial basis (threads 0..15) ----
    if (t < 16) {
        int e = e0 + t;
        int s = esrc[e], d = edst[e];
        float vx = pos[s * 3 + 0] - pos[d * 3 + 0];
        float vy = pos[s * 3 + 1] - pos[d * 3 + 1];
        float vz = pos[s * 3 + 2] - pos[d * 3 + 2];
        float r = sqrtf(vx * vx + vy * vy + vz * vz);
        float invr = 1.0f / r;
        const float sqrt3 = 1.7320508075688772f;
        s_s1[t][0] = sqrt3 * vx * invr;
        s_s1[t][1] = sqrt3 * vy * invr;
        s_s1[t][2] = sqrt3 * vz * invr;
        cutoff[e] = su_f(10.0f * (1.0f - r / RMAXF));
        const float step = RMAXF / 11.0f;
        const float invstep = 11.0f / RMAXF;
        const float K = 26.66929988626f; // 1.14136*e^2*sqrt(10)
        #pragma unroll
        for (int j = 0; j < 10; j++) {
            float dd = (r - step * (float)(j + 1)) * invstep;
            s_emb[t][j] = K * su_f(dd + 1.0f) * su_f(1.0f - dd);
        }
    }
    // ---- phase 1b: stage gathered f[src] and q[dst] rows (round-1) ----
    {
        int el = t >> 4, j = t & 15;
        int e = e0 + el;
        int s = esrc[e], d = edst[e];
        s_g[el][j]      = f[(size_t)s * 32 + j];
        s_g[el][16 + j] = f[(size_t)s * 32 + 16 + j];
        s_q[el][j]      = q[(size_t)d * 32 + j];
        s_q[el][16 + j] = q[(size_t)d * 32 + 16 + j];
    }
    // ---- stage B2 fragments for net 0 (k-net): plain loads + LDS stores ----
    {
        const uint4* src = wsB2;            // net 0 = first 2048 uint4
        #pragma unroll
        for (int it = 0; it < 8; it++) s_B2f[it * 256 + t] = src[it * 256 + t];
    }
    __syncthreads();

    // ---- phase 2: scalar GEMM1 + silu (round-1 math), store bf16 swizzled ----
    {
        const float invsq10 = 0.31622776601683794f; // 1/sqrt(10)
        #pragma unroll
        for (int e = 0; e < 4; e++) {
            int el = wave * 4 + e;
            float ak = 0.0f, av = 0.0f;
            #pragma unroll
            for (int j = 0; j < 10; j++) {
                float ej = s_emb[el][j];
                ak = fmaf(ej, Wk1[j * 64 + lane], ak);
                av = fmaf(ej, Wv1[j * 64 + lane], av);
            }
            ak *= invsq10; av *= invsq10;
            float hk = ak / (1.0f + __expf(-ak));
            float hv = av / (1.0f + __expf(-av));
            // h[el][col=lane] stored at ((col>>3)^(el&7))*8 + (col&7)
            int pos_ = ((((lane >> 3) ^ (el & 7))) << 3) | (lane & 7);
            s_hb[0][el][pos_] = f2bf(hk);
            s_hb[1][el][pos_] = f2bf(hv);
        }
    }
    __syncthreads();

    // ================== net 0 (k-net) ==================
    {
        // A-fragments: edge m = n; kstep s group g = 4s+qd at ((g^(n&7))<<3)
        short8 ha0 = *(const short8*)&s_hb[0][n][((qd ^ (n & 7)) << 3)];
        short8 ha1 = *(const short8*)&s_hb[0][n][(((4 + qd) ^ (n & 7)) << 3)];
        #pragma unroll
        for (int jj = 0; jj < 4; jj++) {
            int tt = wave * 4 + jj;
            short8 b0 = *(const short8*)&s_B2[0][tt][lane];
            short8 b1 = *(const short8*)&s_B2[1][tt][lane];
            f32x4 d = {0.0f, 0.0f, 0.0f, 0.0f};
            d = __builtin_amdgcn_mfma_f32_16x16x32_bf16(ha0, b0, d, 0, 0, 0);
            d = __builtin_amdgcn_mfma_f32_16x16x32_bf16(ha1, b1, d, 0, 0, 0);
            #pragma unroll
            for (int r = 0; r < 4; r++)
                s_w[4 * qd + r][tt * 16 + n] = d[r];   // D: row=4*quad+reg, col=lane&15
        }
    }
    __syncthreads();

    // ---- TP for k-net -> s_k (round-1 phase-4 math) ----
    {
        int el = t >> 4, role = t & 15;
        float s1x = s_s1[el][0], s1y = s_s1[el][1], s1z = s_s1[el][2];
        const float inv_sqrt3 = 0.5773502691896258f;
        float a[8], b[8];
        #pragma unroll
        for (int i = 0; i < 8; i++) {
            a[i] = s_g[el][i];
            b[i] = (s_g[el][8 + i * 3 + 0] * s1x +
                    s_g[el][8 + i * 3 + 1] * s1y +
                    s_g[el][8 + i * 3 + 2] * s1z) * inv_sqrt3;
        }
        const float* wk = s_w[el];
        const float nrm = 0.25f; // 1/(sqrt(8)*sqrt(2))
        if (role < 8) {
            int o = role;
            float ks = 0.0f;
            #pragma unroll
            for (int i = 0; i < 8; i++)
                ks += a[i] * wk[i * 8 + o] + b[i] * wk[64 + i * 8 + o];
            s_k[el][o] = ks * nrm;
        } else {
            int o = role - 8;
            #pragma unroll
            for (int c = 0; c < 3; c++) {
                float uk = 0.0f, tk = 0.0f;
                #pragma unroll
                for (int i = 0; i < 8; i++) {
                    uk += a[i] * wk[128 + i * 8 + o];
                    tk = fmaf(s_g[el][8 + i * 3 + c], wk[192 + i * 8 + o], tk);
                }
                s_k[el][8 + o * 3 + c] = nrm * (s_s1[el][c] * uk + tk);
            }
        }
    }
    __syncthreads();

    // ---- logits (round-1 phase-5 verbatim) ----
    {
        int el = t >> 4, role = t & 15;
        int e = e0 + el;
        const float inv_sqrt3 = 0.5773502691896258f;
        float part = 0.0f;
        #pragma unroll
        for (int kk = 0; kk < 4; kk++) {
            int p = role * 4 + kk;
            int i = p >> 3, j = p & 7;
            float qs_i = s_q[el][i];
            float ks_j = s_k[el][j];
            float dv = s_q[el][8 + i * 3 + 0] * s_k[el][8 + j * 3 + 0]
                     + s_q[el][8 + i * 3 + 1] * s_k[el][8 + j * 3 + 1]
                     + s_q[el][8 + i * 3 + 2] * s_k[el][8 + j * 3 + 2];
            part += qs_i * ks_j * Wds[i * 8 + j] + dv * Wdv[i * 8 + j] * inv_sqrt3;
        }
        part += __shfl_xor(part, 1);
        part += __shfl_xor(part, 2);
        part += __shfl_xor(part, 4);
        part += __shfl_xor(part, 8);
        if (role == 0) logits[e] = part * 0.08838834764831845f; // 1/(8*sqrt(2))
    }
    // ---- restage B2 with net-1 (v-net) fragments ----
    {
        const uint4* src = wsB2 + 2048;
        #pragma unroll
        for (int it = 0; it < 8; it++) s_B2f[it * 256 + t] = src[it * 256 + t];
    }
    __syncthreads();

    // ================== net 1 (v-net) ==================
    {
        short8 ha0 = *(const short8*)&s_hb[1][n][((qd ^ (n & 7)) << 3)];
        short8 ha1 = *(const short8*)&s_hb[1][n][(((4 + qd) ^ (n & 7)) << 3)];
        #pragma unroll
        for (int jj = 0; jj < 4; jj++) {
            int tt = wave * 4 + jj;
            short8 b0 = *(const short8*)&s_B2[0][tt][lane];
            short8 b1 = *(const short8*)&s_B2[1][tt][lane];
            f32x4 d = {0.0f, 0.0f, 0.0f, 0.0f};
            d = __builtin_amdgcn_mfma_f32_16x16x32_bf16(ha0, b0, d, 0, 0, 0);
            d = __builtin_amdgcn_mfma_f32_16x16x32_bf16(ha1, b1, d, 0, 0, 0);
            #pragma unroll
            for (int r = 0; r < 4; r++)
                s_w[4 * qd + r][tt * 16 + n] = d[r];
        }
    }
    __syncthreads();

    // ---- TP for v-net -> vout (round-1 phase-4 math, fp32 out) ----
    {
        int el = t >> 4, role = t & 15;
        int e = e0 + el;
        float s1x = s_s1[el][0], s1y = s_s1[el][1], s1z = s_s1[el][2];
        const float inv_sqrt3 = 0.5773502691896258f;
        float a[8], b[8];
        #pragma unroll
        for (int i = 0; i < 8; i++) {
            a[i] = s_g[el][i];
            b[i] = (s_g[el][8 + i * 3 + 0] * s1x +
                    s_g[el][8 + i * 3 + 1] * s1y +
                    s_g[el][8 + i * 3 + 2] * s1z) * inv_sqrt3;
        }
        const float* wv = s_w[el];
        const float nrm = 0.25f;
        if (role < 8) {
            int o = role;
            float vs = 0.0f;
            #pragma unroll
            for (int i = 0; i < 8; i++)
                vs += a[i] * wv[i * 8 + o] + b[i] * wv[64 + i * 8 + o];
            vout[(size_t)e * 32 + o] = vs * nrm;
        } else {
            int o = role - 8;
            #pragma unroll
            for (int c = 0; c < 3; c++) {
                float uv = 0.0f, tv = 0.0f;
                #pragma unroll
                for (int i = 0; i < 8; i++) {
                    uv += a[i] * wv[128 + i * 8 + o];
                    tv = fmaf(s_g[el][8 + i * 3 + c], wv[192 + i * 8 + o], tv);
                }
                vout[(size_t)e * 32 + 8 + o * 3 + c] = nrm * (s_s1[el][c] * uv + tv);
            }
        }
    }
}

// ---------------------------------------------------------------------------
// out_kernel: round-1 verbatim (fp32 v).
// ---------------------------------------------------------------------------
__global__ __launch_bounds__(256) void out_kernel(
    const float* __restrict__ logits, const float* __restrict__ cutoff,
    const float* __restrict__ v, float* __restrict__ out)
{
    int t = threadIdx.x, wave = t >> 6, lane = t & 63;
    int half = lane >> 5, hl = lane & 31;
    int n = blockIdx.x * 8 + wave * 2 + half;

    float lg = -INFINITY, cw = 0.0f;
    if (hl < DEG) {
        lg = logits[(size_t)n * DEG + hl];
        cw = cutoff[(size_t)n * DEG + hl];
    }
    float mx = lg;
    mx = fmaxf(mx, __shfl_xor(mx, 16));
    mx = fmaxf(mx, __shfl_xor(mx, 8));
    mx = fmaxf(mx, __shfl_xor(mx, 4));
    mx = fmaxf(mx, __shfl_xor(mx, 2));
    mx = fmaxf(mx, __shfl_xor(mx, 1));

    float ew = cw * __expf(lg - mx);
    float z = ew;
    z += __shfl_xor(z, 16);
    z += __shfl_xor(z, 8);
    z += __shfl_xor(z, 4);
    z += __shfl_xor(z, 2);
    z += __shfl_xor(z, 1);
    z = (z == 0.0f) ? 1.0f : z;
    float coef = sqrtf(ew / z + 1e-12f);

    float acc = 0.0f;
    int base = half * 32;
    #pragma unroll
    for (int ee = 0; ee < DEG; ee++) {
        float ce = __shfl(coef, base + ee);
        acc = fmaf(ce, v[((size_t)n * DEG + ee) * 32 + hl], acc);
    }
    out[(size_t)n * 32 + hl] = acc;
}

// ---------------------------------------------------------------------------
extern "C" void kernel_launch(void* const* d_in, const int* in_sizes, int n_in,
                              void* d_out, int out_size, void* d_ws, size_t ws_size,
                              hipStream_t stream) {
    const float* f    = (const float*)d_in[0];
    const float* pos  = (const float*)d_in[1];
    const float* Wqs  = (const float*)d_in[2];
    const float* Wqv  = (const float*)d_in[3];
    const float* Wk1  = (const float*)d_in[4];
    const float* Wk2  = (const float*)d_in[5];
    const float* Wv1  = (const float*)d_in[6];
    const float* Wv2  = (const float*)d_in[7];
    const float* Wds  = (const float*)d_in[8];
    const float* Wdv  = (const float*)d_in[9];
    const int* esrc   = (const int*)d_in[10];
    const int* edst   = (const int*)d_in[11];
    float* out        = (float*)d_out;

    char* ws = (char*)d_ws;
    uint4* wsB2 = (uint4*)(ws);                        // 65536 B
    float* qbuf = (float*)(ws + 65536);                // N*32*4 = 2 MB
    float* lbuf = qbuf + (size_t)NN * 32;              // E
    float* cbuf = lbuf + (size_t)EE;                   // E
    float* vbuf = cbuf + (size_t)EE;                   // E*32

    pack_kernel<<<dim3(16), dim3(256), 0, stream>>>(Wk2, Wv2, wsB2);
    q_kernel<<<dim3((NN * 32) / 256), dim3(256), 0, stream>>>(f, Wqs, Wqv, qbuf);
    edge_kernel<<<dim3(EE / 16), dim3(256), 0, stream>>>(
        f, pos, Wk1, Wv1, Wds, Wdv, esrc, edst, qbuf, wsB2, lbuf, cbuf, vbuf);
    out_kernel<<<dim3(NN / 8), dim3(256), 0, stream>>>(lbuf, cbuf, vbuf, out);
}

// Round 4
// 302.123 us; speedup vs baseline: 1.7050x; 1.1996x over previous
//
#include <hip/hip_runtime.h>
#include <hip/hip_bf16.h>
#include <math.h>

#define NN 16384
#define DEG 20
#define EE (NN*DEG)
#define RMAXF 3.5f
#define NG 4   // edge-groups (of 16) per block

typedef __attribute__((ext_vector_type(8))) short short8;
typedef __attribute__((ext_vector_type(4))) float f32x4;

// soft_unit_step: exp(-1/x) for x>0 else 0
__device__ __forceinline__ float su_f(float x) {
    return x > 0.0f ? __expf(-1.0f / x) : 0.0f;
}
__device__ __forceinline__ ushort f2bf(float x) {
    __hip_bfloat16 h = __float2bfloat16(x);
    return *reinterpret_cast<ushort*>(&h);
}

// ---------------------------------------------------------------------------
// prep_kernel: blocks 0..15 pack W2 B-fragments; blocks 16.. compute q.
// pack: B-frag lane(q=lane>>4, n=lane&15): 8 bf16 = W2[k=s*32+q*8+j][col=tt*16+n]
// wsB2 layout: [net][kstep s][tile tt (16)][lane (64)] as uint4. Scale 1/8.
// ---------------------------------------------------------------------------
__global__ __launch_bounds__(256) void prep_kernel(
    const float* __restrict__ f, const float* __restrict__ Wqs,
    const float* __restrict__ Wqv, const float* __restrict__ Wk2,
    const float* __restrict__ Wv2, uint4* __restrict__ wsB2,
    float* __restrict__ q)
{
    if (blockIdx.x < 16) {
        int tid = blockIdx.x * 256 + threadIdx.x;
        int net = tid >> 11, s = (tid >> 10) & 1, tt = (tid >> 6) & 15, lane = tid & 63;
        int qq = lane >> 4, n = lane & 15, col = tt * 16 + n;
        const float* W2 = net ? Wv2 : Wk2;
        unsigned int r[4];
        #pragma unroll
        for (int jj = 0; jj < 4; jj++) {
            int k0 = s * 32 + qq * 8 + 2 * jj;
            unsigned int lo = f2bf(W2[k0 * 256 + col] * 0.125f);
            unsigned int hi = f2bf(W2[(k0 + 1) * 256 + col] * 0.125f);
            r[jj] = lo | (hi << 16);
        }
        wsB2[tid] = make_uint4(r[0], r[1], r[2], r[3]);
    } else {
        int gid = (blockIdx.x - 16) * 256 + threadIdx.x;
        int n = gid >> 5, k = gid & 31;
        const float* fr = f + (size_t)n * 32;
        float acc = 0.0f;
        if (k < 8) {
            #pragma unroll
            for (int i = 0; i < 8; i++) acc += fr[i] * Wqs[i * 8 + k];
        } else {
            int kk = k - 8;
            int o = kk / 3, c = kk - 3 * (kk / 3);
            #pragma unroll
            for (int i = 0; i < 8; i++) acc += fr[8 + i * 3 + c] * Wqv[i * 8 + o];
        }
        q[(size_t)n * 32 + k] = acc * 0.35355339059327373f; // 1/sqrt(8)
    }
}

// ---------------------------------------------------------------------------
// edge_kernel: 256 threads = 4 waves; NG groups of 16 edges per block.
// B2 fragments live in registers (per-wave tiles); D-matrices for both nets
// resident in LDS. Arithmetic identical to round 3.
// ---------------------------------------------------------------------------
__global__ __launch_bounds__(256, 3) void edge_kernel(
    const float* __restrict__ f,   const float* __restrict__ pos,
    const float* __restrict__ Wk1, const float* __restrict__ Wv1,
    const float* __restrict__ Wds, const float* __restrict__ Wdv,
    const int* __restrict__ esrc,  const int* __restrict__ edst,
    const float* __restrict__ q,   const uint4* __restrict__ wsB2,
    float* __restrict__ logits, float* __restrict__ cutoff,
    float* __restrict__ vout)
{
    __shared__ float  s_w[2][16][261];   // 33.4 KB, D matrices (k,v), pad 261
    __shared__ __align__(16) ushort s_hb[2][16][64];  // 4 KB bf16 h, XOR-swizzled
    __shared__ float s_g[16][32];        // f[src] rows
    __shared__ float s_q[16][32];        // q[dst] rows
    __shared__ float s_k[16][32];        // k tensor-product output
    __shared__ float s_emb[16][10];
    __shared__ float s_s1[16][4];

    const int t = threadIdx.x;
    const int wave = t >> 6, lane = t & 63;
    const int qd = lane >> 4, n = lane & 15;

    // ---- loop-invariant: B fragments for this wave's 4 tiles, both nets ----
    short8 breg[2][2][4]; // [net][kstep][jj]
    #pragma unroll
    for (int net = 0; net < 2; net++)
        #pragma unroll
        for (int s = 0; s < 2; s++)
            #pragma unroll
            for (int jj = 0; jj < 4; jj++)
                breg[net][s][jj] = *(const short8*)&wsB2[net * 2048 + s * 1024 +
                                                         (wave * 4 + jj) * 64 + lane];

    for (int g = 0; g < NG; g++) {
        const int e0 = (blockIdx.x * NG + g) * 16;

        // ---- phase A: geometry + radial basis (threads 0..15) ----
        if (t < 16) {
            int e = e0 + t;
            int s = esrc[e], d = edst[e];
            float vx = pos[s * 3 + 0] - pos[d * 3 + 0];
            float vy = pos[s * 3 + 1] - pos[d * 3 + 1];
            float vz = pos[s * 3 + 2] - pos[d * 3 + 2];
            float r = sqrtf(vx * vx + vy * vy + vz * vz);
            float invr = 1.0f / r;
            const float sqrt3 = 1.7320508075688772f;
            s_s1[t][0] = sqrt3 * vx * invr;
            s_s1[t][1] = sqrt3 * vy * invr;
            s_s1[t][2] = sqrt3 * vz * invr;
            cutoff[e] = su_f(10.0f * (1.0f - r / RMAXF));
            const float step = RMAXF / 11.0f;
            const float invstep = 11.0f / RMAXF;
            const float K = 26.66929988626f; // 1.14136*e^2*sqrt(10)
            #pragma unroll
            for (int j = 0; j < 10; j++) {
                float dd = (r - step * (float)(j + 1)) * invstep;
                s_emb[t][j] = K * su_f(dd + 1.0f) * su_f(1.0f - dd);
            }
        }
        // ---- phase A2: stage gathered f[src] and q[dst] rows ----
        {
            int el = t >> 4, j = t & 15;
            int e = e0 + el;
            int s = esrc[e], d = edst[e];
            s_g[el][j]      = f[(size_t)s * 32 + j];
            s_g[el][16 + j] = f[(size_t)s * 32 + 16 + j];
            s_q[el][j]      = q[(size_t)d * 32 + j];
            s_q[el][16 + j] = q[(size_t)d * 32 + 16 + j];
        }
        __syncthreads();

        // ---- phase B: scalar GEMM1 + silu -> s_hb (bf16, swizzled) ----
        {
            const float invsq10 = 0.31622776601683794f; // 1/sqrt(10)
            #pragma unroll
            for (int e = 0; e < 4; e++) {
                int el = wave * 4 + e;
                float ak = 0.0f, av = 0.0f;
                #pragma unroll
                for (int j = 0; j < 10; j++) {
                    float ej = s_emb[el][j];
                    ak = fmaf(ej, Wk1[j * 64 + lane], ak);
                    av = fmaf(ej, Wv1[j * 64 + lane], av);
                }
                ak *= invsq10; av *= invsq10;
                float hk = ak / (1.0f + __expf(-ak));
                float hv = av / (1.0f + __expf(-av));
                int pos_ = ((((lane >> 3) ^ (el & 7))) << 3) | (lane & 7);
                s_hb[0][el][pos_] = f2bf(hk);
                s_hb[1][el][pos_] = f2bf(hv);
            }
        }
        __syncthreads();

        // ---- phase C: MFMA GEMM2 for both nets -> s_w[net] ----
        #pragma unroll
        for (int net = 0; net < 2; net++) {
            short8 ha0 = *(const short8*)&s_hb[net][n][((qd ^ (n & 7)) << 3)];
            short8 ha1 = *(const short8*)&s_hb[net][n][(((4 + qd) ^ (n & 7)) << 3)];
            #pragma unroll
            for (int jj = 0; jj < 4; jj++) {
                int tt = wave * 4 + jj;
                f32x4 d = {0.0f, 0.0f, 0.0f, 0.0f};
                d = __builtin_amdgcn_mfma_f32_16x16x32_bf16(ha0, breg[net][0][jj], d, 0, 0, 0);
                d = __builtin_amdgcn_mfma_f32_16x16x32_bf16(ha1, breg[net][1][jj], d, 0, 0, 0);
                #pragma unroll
                for (int r = 0; r < 4; r++)
                    s_w[net][4 * qd + r][tt * 16 + n] = d[r]; // D: row=4*quad+reg, col=n
            }
        }
        __syncthreads();

        // ---- phase D: TP for k-net -> s_k ----
        {
            int el = t >> 4, role = t & 15;
            float s1x = s_s1[el][0], s1y = s_s1[el][1], s1z = s_s1[el][2];
            const float inv_sqrt3 = 0.5773502691896258f;
            float a[8], b[8];
            #pragma unroll
            for (int i = 0; i < 8; i++) {
                a[i] = s_g[el][i];
                b[i] = (s_g[el][8 + i * 3 + 0] * s1x +
                        s_g[el][8 + i * 3 + 1] * s1y +
                        s_g[el][8 + i * 3 + 2] * s1z) * inv_sqrt3;
            }
            const float* wk = s_w[0][el];
            const float nrm = 0.25f; // 1/(sqrt(8)*sqrt(2))
            if (role < 8) {
                int o = role;
                float ks = 0.0f;
                #pragma unroll
                for (int i = 0; i < 8; i++)
                    ks += a[i] * wk[i * 8 + o] + b[i] * wk[64 + i * 8 + o];
                s_k[el][o] = ks * nrm;
            } else {
                int o = role - 8;
                #pragma unroll
                for (int c = 0; c < 3; c++) {
                    float uk = 0.0f, tk = 0.0f;
                    #pragma unroll
                    for (int i = 0; i < 8; i++) {
                        uk += a[i] * wk[128 + i * 8 + o];
                        tk = fmaf(s_g[el][8 + i * 3 + c], wk[192 + i * 8 + o], tk);
                    }
                    s_k[el][8 + o * 3 + c] = nrm * (s_s1[el][c] * uk + tk);
                }
            }
        }
        __syncthreads();

        // ---- phase E: logits + TP for v-net -> vout ----
        {
            int el = t >> 4, role = t & 15;
            int e = e0 + el;
            const float inv_sqrt3 = 0.5773502691896258f;
            float part = 0.0f;
            #pragma unroll
            for (int kk = 0; kk < 4; kk++) {
                int p = role * 4 + kk;
                int i = p >> 3, j = p & 7;
                float qs_i = s_q[el][i];
                float ks_j = s_k[el][j];
                float dv = s_q[el][8 + i * 3 + 0] * s_k[el][8 + j * 3 + 0]
                         + s_q[el][8 + i * 3 + 1] * s_k[el][8 + j * 3 + 1]
                         + s_q[el][8 + i * 3 + 2] * s_k[el][8 + j * 3 + 2];
                part += qs_i * ks_j * Wds[i * 8 + j] + dv * Wdv[i * 8 + j] * inv_sqrt3;
            }
            part += __shfl_xor(part, 1);
            part += __shfl_xor(part, 2);
            part += __shfl_xor(part, 4);
            part += __shfl_xor(part, 8);
            if (role == 0) logits[e] = part * 0.08838834764831845f; // 1/(8*sqrt(2))

            // TP v-net (same thread mapping, reads s_w[1], s_g, s_s1)
            float s1x = s_s1[el][0], s1y = s_s1[el][1], s1z = s_s1[el][2];
            float a[8], b[8];
            #pragma unroll
            for (int i = 0; i < 8; i++) {
                a[i] = s_g[el][i];
                b[i] = (s_g[el][8 + i * 3 + 0] * s1x +
                        s_g[el][8 + i * 3 + 1] * s1y +
                        s_g[el][8 + i * 3 + 2] * s1z) * inv_sqrt3;
            }
            const float* wv = s_w[1][el];
            const float nrm = 0.25f;
            if (role < 8) {
                int o = role;
                float vs = 0.0f;
                #pragma unroll
                for (int i = 0; i < 8; i++)
                    vs += a[i] * wv[i * 8 + o] + b[i] * wv[64 + i * 8 + o];
                vout[(size_t)e * 32 + o] = vs * nrm;
            } else {
                int o = role - 8;
                #pragma unroll
                for (int c = 0; c < 3; c++) {
                    float uv = 0.0f, tv = 0.0f;
                    #pragma unroll
                    for (int i = 0; i < 8; i++) {
                        uv += a[i] * wv[128 + i * 8 + o];
                        tv = fmaf(s_g[el][8 + i * 3 + c], wv[192 + i * 8 + o], tv);
                    }
                    vout[(size_t)e * 32 + 8 + o * 3 + c] = nrm * (s_s1[el][c] * uv + tv);
                }
            }
        }
        __syncthreads(); // protect s_* before next group's phase A
    }
}

// ---------------------------------------------------------------------------
// out_kernel: one half-wave (32 lanes) per node (round-1 verbatim, fp32 v).
// ---------------------------------------------------------------------------
__global__ __launch_bounds__(256) void out_kernel(
    const float* __restrict__ logits, const float* __restrict__ cutoff,
    const float* __restrict__ v, float* __restrict__ out)
{
    int t = threadIdx.x, wave = t >> 6, lane = t & 63;
    int half = lane >> 5, hl = lane & 31;
    int n = blockIdx.x * 8 + wave * 2 + half;

    float lg = -INFINITY, cw = 0.0f;
    if (hl < DEG) {
        lg = logits[(size_t)n * DEG + hl];
        cw = cutoff[(size_t)n * DEG + hl];
    }
    float mx = lg;
    mx = fmaxf(mx, __shfl_xor(mx, 16));
    mx = fmaxf(mx, __shfl_xor(mx, 8));
    mx = fmaxf(mx, __shfl_xor(mx, 4));
    mx = fmaxf(mx, __shfl_xor(mx, 2));
    mx = fmaxf(mx, __shfl_xor(mx, 1));

    float ew = cw * __expf(lg - mx);
    float z = ew;
    z += __shfl_xor(z, 16);
    z += __shfl_xor(z, 8);
    z += __shfl_xor(z, 4);
    z += __shfl_xor(z, 2);
    z += __shfl_xor(z, 1);
    z = (z == 0.0f) ? 1.0f : z;
    float coef = sqrtf(ew / z + 1e-12f);

    float acc = 0.0f;
    int base = half * 32;
    #pragma unroll
    for (int ee = 0; ee < DEG; ee++) {
        float ce = __shfl(coef, base + ee);
        acc = fmaf(ce, v[((size_t)n * DEG + ee) * 32 + hl], acc);
    }
    out[(size_t)n * 32 + hl] = acc;
}

// ---------------------------------------------------------------------------
extern "C" void kernel_launch(void* const* d_in, const int* in_sizes, int n_in,
                              void* d_out, int out_size, void* d_ws, size_t ws_size,
                              hipStream_t stream) {
    const float* f    = (const float*)d_in[0];
    const float* pos  = (const float*)d_in[1];
    const float* Wqs  = (const float*)d_in[2];
    const float* Wqv  = (const float*)d_in[3];
    const float* Wk1  = (const float*)d_in[4];
    const float* Wk2  = (const float*)d_in[5];
    const float* Wv1  = (const float*)d_in[6];
    const float* Wv2  = (const float*)d_in[7];
    const float* Wds  = (const float*)d_in[8];
    const float* Wdv  = (const float*)d_in[9];
    const int* esrc   = (const int*)d_in[10];
    const int* edst   = (const int*)d_in[11];
    float* out        = (float*)d_out;

    char* ws = (char*)d_ws;
    uint4* wsB2 = (uint4*)(ws);                        // 65536 B
    float* qbuf = (float*)(ws + 65536);                // N*32*4 = 2 MB
    float* lbuf = qbuf + (size_t)NN * 32;              // E
    float* cbuf = lbuf + (size_t)EE;                   // E
    float* vbuf = cbuf + (size_t)EE;                   // E*32

    prep_kernel<<<dim3(16 + (NN * 32) / 256), dim3(256), 0, stream>>>(
        f, Wqs, Wqv, Wk2, Wv2, wsB2, qbuf);
    edge_kernel<<<dim3(EE / (16 * NG)), dim3(256), 0, stream>>>(
        f, pos, Wk1, Wv1, Wds, Wdv, esrc, edst, qbuf, wsB2, lbuf, cbuf, vbuf);
    out_kernel<<<dim3(NN / 8), dim3(256), 0, stream>>>(lbuf, cbuf, vbuf, out);
}

// Round 6
// 252.309 us; speedup vs baseline: 2.0416x; 1.1974x over previous
//
#include <hip/hip_runtime.h>
#include <hip/hip_bf16.h>
#include <math.h>

#define NN 16384
#define DEG 20
#define EE (NN*DEG)
#define RMAXF 3.5f
#define NG 4   // edge-groups (of 16) per block

typedef __attribute__((ext_vector_type(8))) short short8;
typedef __attribute__((ext_vector_type(4))) float f32x4;

// soft_unit_step: exp(-1/x) for x>0 else 0
__device__ __forceinline__ float su_f(float x) {
    return x > 0.0f ? __expf(-1.0f / x) : 0.0f;
}
__device__ __forceinline__ ushort f2bf(float x) {
    __hip_bfloat16 h = __float2bfloat16(x);
    return *reinterpret_cast<ushort*>(&h);
}

// ---------------------------------------------------------------------------
// prep_kernel: blocks 0..15 pack W2 B-fragments (round-4 proven); blocks 16..
// compute per-node logit vectors mq:
//   mq[n][j]       = sum_i qs_i * Wd_s[i][j]               (j<8)
//   mq[n][8+3j+c]  = (sum_i qv_i[c] * Wd_v[i][j]) / sqrt3
// ---------------------------------------------------------------------------
__global__ __launch_bounds__(256) void prep_kernel(
    const float* __restrict__ f, const float* __restrict__ Wqs,
    const float* __restrict__ Wqv, const float* __restrict__ Wk2,
    const float* __restrict__ Wv2, const float* __restrict__ Wds,
    const float* __restrict__ Wdv, uint4* __restrict__ wsB2,
    float* __restrict__ mq)
{
    if (blockIdx.x < 16) {
        int tid = blockIdx.x * 256 + threadIdx.x;
        int net = tid >> 11, s = (tid >> 10) & 1, tt = (tid >> 6) & 15, lane = tid & 63;
        int qq = lane >> 4, n = lane & 15, col = tt * 16 + n;
        const float* W2 = net ? Wv2 : Wk2;
        unsigned int r[4];
        #pragma unroll
        for (int jj = 0; jj < 4; jj++) {
            int k0 = s * 32 + qq * 8 + 2 * jj;
            unsigned int lo = f2bf(W2[k0 * 256 + col] * 0.125f);
            unsigned int hi = f2bf(W2[(k0 + 1) * 256 + col] * 0.125f);
            r[jj] = lo | (hi << 16);
        }
        wsB2[tid] = make_uint4(r[0], r[1], r[2], r[3]);
    } else {
        int gid = (blockIdx.x - 16) * 256 + threadIdx.x;
        int nn = gid >> 5, idx = gid & 31;
        const float* fr = f + (size_t)nn * 32;
        const float inv8 = 0.35355339059327373f; // 1/sqrt(8)
        float out = 0.0f;
        if (idx < 8) {
            int j = idx;
            #pragma unroll
            for (int i = 0; i < 8; i++) {
                float qs = 0.0f;
                #pragma unroll
                for (int a = 0; a < 8; a++) qs = fmaf(fr[a], Wqs[a * 8 + i], qs);
                out = fmaf(qs * inv8, Wds[i * 8 + j], out);
            }
        } else {
            int kk = idx - 8;
            int j = kk / 3, c = kk - 3 * j;
            #pragma unroll
            for (int i = 0; i < 8; i++) {
                float qv = 0.0f;
                #pragma unroll
                for (int a = 0; a < 8; a++) qv = fmaf(fr[8 + 3 * a + c], Wqv[a * 8 + i], qv);
                out = fmaf(qv * inv8, Wdv[i * 8 + j], out);
            }
            out *= 0.5773502691896258f; // 1/sqrt(3)
        }
        mq[(size_t)nn * 32 + idx] = out;
    }
}

// ---------------------------------------------------------------------------
// edge_kernel: round-4 structure verbatim (passing), with ONLY the logits
// path changed: s_q -> s_mq, phase-D dot-TP against q replaced by direct
// contraction of ks/kv with mq. s_w TP unchanged.
// ---------------------------------------------------------------------------
__global__ __launch_bounds__(256, 3) void edge_kernel(
    const float* __restrict__ f,   const float* __restrict__ pos,
    const float* __restrict__ Wk1, const float* __restrict__ Wv1,
    const int* __restrict__ esrc,  const int* __restrict__ edst,
    const float* __restrict__ mq,  const uint4* __restrict__ wsB2,
    float* __restrict__ logits, float* __restrict__ cutoff,
    float* __restrict__ vout)
{
    __shared__ float  s_w[2][16][261];   // 33.4 KB, D matrices (k,v), pad 261
    __shared__ __align__(16) ushort s_hb[2][16][64];  // 4 KB bf16 h, XOR-swizzled
    __shared__ float s_g[16][32];        // f[src] rows
    __shared__ float s_mq[16][32];       // mq[dst] rows
    __shared__ float s_emb[16][10];
    __shared__ float s_s1[16][4];

    const int t = threadIdx.x;
    const int wave = t >> 6, lane = t & 63;
    const int qd = lane >> 4, n = lane & 15;

    // ---- loop-invariant: B fragments for this wave's 4 tiles, both nets ----
    short8 breg[2][2][4]; // [net][kstep][jj]
    #pragma unroll
    for (int net = 0; net < 2; net++)
        #pragma unroll
        for (int s = 0; s < 2; s++)
            #pragma unroll
            for (int jj = 0; jj < 4; jj++)
                breg[net][s][jj] = *(const short8*)&wsB2[net * 2048 + s * 1024 +
                                                         (wave * 4 + jj) * 64 + lane];

    for (int g = 0; g < NG; g++) {
        const int e0 = (blockIdx.x * NG + g) * 16;

        // ---- phase A: geometry + radial basis (threads 0..15) ----
        if (t < 16) {
            int e = e0 + t;
            int s = esrc[e], d = edst[e];
            float vx = pos[s * 3 + 0] - pos[d * 3 + 0];
            float vy = pos[s * 3 + 1] - pos[d * 3 + 1];
            float vz = pos[s * 3 + 2] - pos[d * 3 + 2];
            float r = sqrtf(vx * vx + vy * vy + vz * vz);
            float invr = 1.0f / r;
            const float sqrt3 = 1.7320508075688772f;
            s_s1[t][0] = sqrt3 * vx * invr;
            s_s1[t][1] = sqrt3 * vy * invr;
            s_s1[t][2] = sqrt3 * vz * invr;
            cutoff[e] = su_f(10.0f * (1.0f - r / RMAXF));
            const float step = RMAXF / 11.0f;
            const float invstep = 11.0f / RMAXF;
            const float K = 26.66929988626f; // 1.14136*e^2*sqrt(10)
            #pragma unroll
            for (int j = 0; j < 10; j++) {
                float dd = (r - step * (float)(j + 1)) * invstep;
                s_emb[t][j] = K * su_f(dd + 1.0f) * su_f(1.0f - dd);
            }
        }
        // ---- phase A2: stage gathered f[src] and mq[dst] rows ----
        {
            int el = t >> 4, j = t & 15;
            int e = e0 + el;
            int s = esrc[e], d = edst[e];
            s_g[el][j]       = f[(size_t)s * 32 + j];
            s_g[el][16 + j]  = f[(size_t)s * 32 + 16 + j];
            s_mq[el][j]      = mq[(size_t)d * 32 + j];
            s_mq[el][16 + j] = mq[(size_t)d * 32 + 16 + j];
        }
        __syncthreads();

        // ---- phase B: scalar GEMM1 + silu -> s_hb (bf16, swizzled) ----
        {
            const float invsq10 = 0.31622776601683794f; // 1/sqrt(10)
            #pragma unroll
            for (int e = 0; e < 4; e++) {
                int el = wave * 4 + e;
                float ak = 0.0f, av = 0.0f;
                #pragma unroll
                for (int j = 0; j < 10; j++) {
                    float ej = s_emb[el][j];
                    ak = fmaf(ej, Wk1[j * 64 + lane], ak);
                    av = fmaf(ej, Wv1[j * 64 + lane], av);
                }
                ak *= invsq10; av *= invsq10;
                float hk = ak / (1.0f + __expf(-ak));
                float hv = av / (1.0f + __expf(-av));
                int pos_ = ((((lane >> 3) ^ (el & 7))) << 3) | (lane & 7);
                s_hb[0][el][pos_] = f2bf(hk);
                s_hb[1][el][pos_] = f2bf(hv);
            }
        }
        __syncthreads();

        // ---- phase C: MFMA GEMM2 for both nets -> s_w[net] ----
        #pragma unroll
        for (int net = 0; net < 2; net++) {
            short8 ha0 = *(const short8*)&s_hb[net][n][((qd ^ (n & 7)) << 3)];
            short8 ha1 = *(const short8*)&s_hb[net][n][(((4 + qd) ^ (n & 7)) << 3)];
            #pragma unroll
            for (int jj = 0; jj < 4; jj++) {
                int tt = wave * 4 + jj;
                f32x4 d = {0.0f, 0.0f, 0.0f, 0.0f};
                d = __builtin_amdgcn_mfma_f32_16x16x32_bf16(ha0, breg[net][0][jj], d, 0, 0, 0);
                d = __builtin_amdgcn_mfma_f32_16x16x32_bf16(ha1, breg[net][1][jj], d, 0, 0, 0);
                #pragma unroll
                for (int r = 0; r < 4; r++)
                    s_w[net][4 * qd + r][tt * 16 + n] = d[r]; // D: row=4*quad+reg, col=n
            }
        }
        __syncthreads();

        // ---- phase D: k-net TP + mq-logits; v-net TP -> vout (merged) ----
        {
            int el = t >> 4, role = t & 15;
            int e = e0 + el;
            float s1x = s_s1[el][0], s1y = s_s1[el][1], s1z = s_s1[el][2];
            const float inv_sqrt3 = 0.5773502691896258f;
            float a[8], b[8];
            #pragma unroll
            for (int i = 0; i < 8; i++) {
                a[i] = s_g[el][i];
                b[i] = (s_g[el][8 + i * 3 + 0] * s1x +
                        s_g[el][8 + i * 3 + 1] * s1y +
                        s_g[el][8 + i * 3 + 2] * s1z) * inv_sqrt3;
            }
            const float nrm = 0.25f; // 1/(sqrt(8)*sqrt(2))

            // --- k-net: compute this role's ks/kv and contract with mq ---
            const float* wk = s_w[0][el];
            float contrib = 0.0f;
            if (role < 8) {
                int o = role;
                float ks = 0.0f;
                #pragma unroll
                for (int i = 0; i < 8; i++)
                    ks += a[i] * wk[i * 8 + o] + b[i] * wk[64 + i * 8 + o];
                contrib = s_mq[el][o] * (ks * nrm);
            } else {
                int o = role - 8;
                #pragma unroll
                for (int c = 0; c < 3; c++) {
                    float uk = 0.0f, tk = 0.0f;
                    #pragma unroll
                    for (int i = 0; i < 8; i++) {
                        uk += a[i] * wk[128 + i * 8 + o];
                        tk = fmaf(s_g[el][8 + i * 3 + c], wk[192 + i * 8 + o], tk);
                    }
                    float kv_c = nrm * (s_s1[el][c] * uk + tk);
                    contrib = fmaf(s_mq[el][8 + 3 * o + c], kv_c, contrib);
                }
            }
            contrib += __shfl_xor(contrib, 1);
            contrib += __shfl_xor(contrib, 2);
            contrib += __shfl_xor(contrib, 4);
            contrib += __shfl_xor(contrib, 8);
            if (role == 0) logits[e] = contrib * 0.08838834764831845f; // 1/(8*sqrt(2))

            // --- v-net TP -> vout (round-4 phase E verbatim) ---
            const float* wv = s_w[1][el];
            if (role < 8) {
                int o = role;
                float vs = 0.0f;
                #pragma unroll
                for (int i = 0; i < 8; i++)
                    vs += a[i] * wv[i * 8 + o] + b[i] * wv[64 + i * 8 + o];
                vout[(size_t)e * 32 + o] = vs * nrm;
            } else {
                int o = role - 8;
                #pragma unroll
                for (int c = 0; c < 3; c++) {
                    float uv = 0.0f, tv = 0.0f;
                    #pragma unroll
                    for (int i = 0; i < 8; i++) {
                        uv += a[i] * wv[128 + i * 8 + o];
                        tv = fmaf(s_g[el][8 + i * 3 + c], wv[192 + i * 8 + o], tv);
                    }
                    vout[(size_t)e * 32 + 8 + o * 3 + c] = nrm * (s_s1[el][c] * uv + tv);
                }
            }
        }
        __syncthreads(); // protect s_* before next group's phase A
    }
}

// ---------------------------------------------------------------------------
// out_kernel: one half-wave (32 lanes) per node (proven, fp32 v).
// ---------------------------------------------------------------------------
__global__ __launch_bounds__(256) void out_kernel(
    const float* __restrict__ logits, const float* __restrict__ cutoff,
    const float* __restrict__ v, float* __restrict__ out)
{
    int t = threadIdx.x, wave = t >> 6, lane = t & 63;
    int half = lane >> 5, hl = lane & 31;
    int n = blockIdx.x * 8 + wave * 2 + half;

    float lg = -INFINITY, cw = 0.0f;
    if (hl < DEG) {
        lg = logits[(size_t)n * DEG + hl];
        cw = cutoff[(size_t)n * DEG + hl];
    }
    float mx = lg;
    mx = fmaxf(mx, __shfl_xor(mx, 16));
    mx = fmaxf(mx, __shfl_xor(mx, 8));
    mx = fmaxf(mx, __shfl_xor(mx, 4));
    mx = fmaxf(mx, __shfl_xor(mx, 2));
    mx = fmaxf(mx, __shfl_xor(mx, 1));

    float ew = cw * __expf(lg - mx);
    float z = ew;
    z += __shfl_xor(z, 16);
    z += __shfl_xor(z, 8);
    z += __shfl_xor(z, 4);
    z += __shfl_xor(z, 2);
    z += __shfl_xor(z, 1);
    z = (z == 0.0f) ? 1.0f : z;
    float coef = sqrtf(ew / z + 1e-12f);

    float acc = 0.0f;
    int base = half * 32;
    #pragma unroll
    for (int ee = 0; ee < DEG; ee++) {
        float ce = __shfl(coef, base + ee);
        acc = fmaf(ce, v[((size_t)n * DEG + ee) * 32 + hl], acc);
    }
    out[(size_t)n * 32 + hl] = acc;
}

// ---------------------------------------------------------------------------
extern "C" void kernel_launch(void* const* d_in, const int* in_sizes, int n_in,
                              void* d_out, int out_size, void* d_ws, size_t ws_size,
                              hipStream_t stream) {
    const float* f    = (const float*)d_in[0];
    const float* pos  = (const float*)d_in[1];
    const float* Wqs  = (const float*)d_in[2];
    const float* Wqv  = (const float*)d_in[3];
    const float* Wk1  = (const float*)d_in[4];
    const float* Wk2  = (const float*)d_in[5];
    const float* Wv1  = (const float*)d_in[6];
    const float* Wv2  = (const float*)d_in[7];
    const float* Wds  = (const float*)d_in[8];
    const float* Wdv  = (const float*)d_in[9];
    const int* esrc   = (const int*)d_in[10];
    const int* edst   = (const int*)d_in[11];
    float* out        = (float*)d_out;

    char* ws = (char*)d_ws;
    uint4* wsB2  = (uint4*)(ws);                       // 65536 B
    float* mqbuf = (float*)(ws + 65536);               // N*32*4 = 2 MB
    float* lbuf  = mqbuf + (size_t)NN * 32;            // E
    float* cbuf  = lbuf + (size_t)EE;                  // E
    float* vbuf  = cbuf + (size_t)EE;                  // E*32

    prep_kernel<<<dim3(16 + (NN * 32) / 256), dim3(256), 0, stream>>>(
        f, Wqs, Wqv, Wk2, Wv2, Wds, Wdv, wsB2, mqbuf);
    edge_kernel<<<dim3(EE / (16 * NG)), dim3(256), 0, stream>>>(
        f, pos, Wk1, Wv1, esrc, edst, mqbuf, wsB2, lbuf, cbuf, vbuf);
    out_kernel<<<dim3(NN / 8), dim3(256), 0, stream>>>(lbuf, cbuf, vbuf, out);
}